// Round 6
// baseline (244.446 us; speedup 1.0000x reference)
//
#include <hip/hip_runtime.h>
#include <hip/hip_bf16.h>

#define BATCH 8
#define NC 2048
#define NF 8192
#define CDIM 256
#define CSKIP 64
#define OUTD 256
#define MTOT (BATCH*NF)   // 65536
#define NCTOT (BATCH*NC)  // 16384
#define KCH 1024          // per-half coarse chunk

typedef __attribute__((ext_vector_type(8))) short short8;
typedef __attribute__((ext_vector_type(4))) float floatx4;

static __device__ __forceinline__ ushort f2bf(float f) {
    union { float f; unsigned u; } v; v.f = f;
    unsigned r = v.u + 0x7fffu + ((v.u >> 16) & 1u);   // RNE
    return (ushort)(r >> 16);
}
static __device__ __forceinline__ float bf2f(ushort u) {
    union { unsigned u; float f; } v; v.u = ((unsigned)u) << 16;
    return v.f;
}

#if defined(__has_builtin) && __has_builtin(__builtin_amdgcn_fmed3f)
#define MED3F(a, b, c) __builtin_amdgcn_fmed3f((a), (b), (c))
#else
static __device__ __forceinline__ float MED3F(float a, float b, float c) {
    return fmaxf(fminf(a, b), fminf(fmaxf(a, b), c));
}
#endif

// branchless strict-< top-3 insert, parametrized state (exact jax top_k tie order
// when fed ascending j)
#define TOP3_INS(d, jj, D0, D1, D2, I0, I1, I2)     \
    {                                               \
        bool c2 = (d) < D2, c1 = (d) < D1, c0 = (d) < D0; \
        I2 = c1 ? I1 : (c2 ? (jj) : I2);            \
        I1 = c0 ? I0 : (c1 ? (jj) : I1);            \
        I0 = c0 ? (jj) : I0;                        \
        D2 = MED3F(D1, D2, (d));                    \
        D1 = MED3F(D0, D1, (d));                    \
        D0 = fminf(D0, (d));                        \
    }

// ---- kernel 1: prep (bf16 casts of x / x_skip, pos padding, tail outputs)
#define SEG0 1048576   // x -> xb bf16 (float4-wide)
#define SEG1 1048576   // x_skip -> xsb bf16
#define SEG5 16384     // pos -> pos4
#define SEG6 (MTOT*3)  // pos_skip -> out tail
#define SEG7 MTOT      // batch ids -> out tail
#define PREP_THREADS (SEG0+SEG1+SEG5+SEG6+SEG7)

__global__ __launch_bounds__(256) void prep_kernel(const float* __restrict__ x,
                                                   const float* __restrict__ x_skip,
                                                   const float* __restrict__ pos,
                                                   const float* __restrict__ pos_skip,
                                                   ushort* __restrict__ xb,
                                                   ushort* __restrict__ xsb,
                                                   float4* __restrict__ pos4,
                                                   float* __restrict__ out) {
    int t = blockIdx.x * 256 + threadIdx.x;
    if (t < SEG0) {
        float4 v = ((const float4*)x)[t];
        ushort4 p; p.x = f2bf(v.x); p.y = f2bf(v.y); p.z = f2bf(v.z); p.w = f2bf(v.w);
        ((ushort4*)xb)[t] = p;
        return;
    }
    t -= SEG0;
    if (t < SEG1) {
        float4 v = ((const float4*)x_skip)[t];
        ushort4 p; p.x = f2bf(v.x); p.y = f2bf(v.y); p.z = f2bf(v.z); p.w = f2bf(v.w);
        ((ushort4*)xsb)[t] = p;
        return;
    }
    t -= SEG1;
    if (t < SEG5) {
        float4 q;
        q.x = pos[t * 3 + 0]; q.y = pos[t * 3 + 1]; q.z = pos[t * 3 + 2]; q.w = 0.f;
        pos4[t] = q;
        return;
    }
    t -= SEG5;
    if (t < SEG6) {
        out[(size_t)MTOT * OUTD + t] = pos_skip[t];
        return;
    }
    t -= SEG6;
    if (t < SEG7) {
        out[(size_t)MTOT * OUTD + (size_t)MTOT * 3 + t] = (float)(t >> 13);
    }
}

// ---- kernel 1b: LDS-tiled weight transpose (coalesced read AND write).
__global__ __launch_bounds__(256) void prep_w(const float* __restrict__ W1,
                                              const float* __restrict__ W2,
                                              ushort* __restrict__ Bt1a,
                                              ushort* __restrict__ Bt1b,
                                              ushort* __restrict__ Bt2) {
    __shared__ ushort tile[64 * 65];
    int bid = blockIdx.x;
    const float* src; ushort* dst; int k0, n0, KD;
    if (bid < 16)      { src = W1;             dst = Bt1a; k0 = (bid >> 2) * 64; n0 = (bid & 3) * 64; KD = 256; }
    else if (bid < 20) { src = W1 + 256 * 256; dst = Bt1b; k0 = 0;               n0 = (bid - 16) * 64; KD = 64; }
    else               { int b2 = bid - 20; src = W2; dst = Bt2; k0 = (b2 >> 2) * 64; n0 = (b2 & 3) * 64; KD = 256; }
    int tx = threadIdx.x & 63, ty = threadIdx.x >> 6;
#pragma unroll
    for (int r = 0; r < 64; r += 4) {
        int k = r + ty;
        tile[k * 65 + tx] = f2bf(src[(size_t)(k0 + k) * 256 + n0 + tx]);
    }
    __syncthreads();
#pragma unroll
    for (int r = 0; r < 64; r += 4) {
        int n = r + ty;
        dst[(size_t)(n0 + n) * KD + k0 + tx] = tile[tx * 65 + n];
    }
}

// ---- kernel 2: fused 2-way-chunk kNN, PROVABLY-uniform scalar candidate feed.
// Round-3 failed because half=tid>>8 / cloud=m>>13 were wave-uniform in fact
// but not provably (threadIdx-derived) -> loads stayed flat VMEM, latency
// bound at 52%. Round-5 dual-pipe added VALU overhead (42->51us busy-time).
// Fix: cloud = blockIdx.x>>5 (uniform by construction) and half =
// readfirstlane(tid>>8) (SGPR by definition) -> candidate addresses and
// insert index jj are pure scalar expressions -> s_load path (zero VALU,
// zero LDS, own lgkm queue); VALU ops take the SGPR operand directly.
// Depth-1 register prefetch hedges the case where scalarization fails
// (r3 had none). pos4 padded +8 so the prefetch needs no tail guard.
// Distance math, scan order, guarded insert, merge semantics identical to
// the passing rounds.
__global__ __launch_bounds__(512) void knn_fused(const float4* __restrict__ pos4,
                                                 const float* __restrict__ pos_skip,
                                                 int* __restrict__ idxw,
                                                 float* __restrict__ wgt) {
    __shared__ float pd[256 * 3];              // 3 KB
    __shared__ int   pi[256 * 3];              // 3 KB
    int tid = threadIdx.x;
    int half = __builtin_amdgcn_readfirstlane(tid >> 8);  // provably uniform
    int tl = tid & 255;
    int bcloud = blockIdx.x >> 5;              // 32 blocks/cloud — uniform
    int jbase = bcloud * NC;
    int m = blockIdx.x * 256 + tl;

    float px = pos_skip[m * 3 + 0];
    float py = pos_skip[m * 3 + 1];
    float pz = pos_skip[m * 3 + 2];

    int joff = half * KCH;
    const float4* cand = pos4 + jbase + joff;  // uniform (SGPR) base

    float d0 = 1e30f, d1 = 1e30f, d2 = 1e30f;
    int i0 = jbase, i1 = jbase, i2 = jbase;

    float4 qc[8], qn[8];
#pragma unroll
    for (int u = 0; u < 8; ++u) qc[u] = cand[u];

    for (int j8 = 0; j8 < KCH; j8 += 8) {
        // prefetch next group (reads into pad on last iter; discarded)
#pragma unroll
        for (int u = 0; u < 8; ++u) qn[u] = cand[j8 + 8 + u];
        float dd[8];
#pragma unroll
        for (int u = 0; u < 8; ++u) {
            float ax = px - qc[u].x, ay = py - qc[u].y, az = pz - qc[u].z;
            dd[u] = ax * ax + ay * ay + az * az;
        }
#pragma unroll
        for (int u = 0; u < 8; ++u) {
            if (__any(dd[u] < d2)) {
                int jj = jbase + joff + j8 + u;      // uniform (SGPR) index
                TOP3_INS(dd[u], jj, d0, d1, d2, i0, i1, i2);
            }
        }
#pragma unroll
        for (int u = 0; u < 8; ++u) qc[u] = qn[u];
    }

    if (half) {
        pd[tl * 3 + 0] = d0; pd[tl * 3 + 1] = d1; pd[tl * 3 + 2] = d2;
        pi[tl * 3 + 0] = i0; pi[tl * 3 + 1] = i1; pi[tl * 3 + 2] = i2;
    }
    __syncthreads();
    if (!half) {
        // merge half-1 partials in ascending-distance order (ties: lower j
        // first inside each half; all half-0 j < half-1 j) -> jax order.
#pragma unroll
        for (int s = 0; s < 3; ++s) {
            float d = pd[tl * 3 + s];
            int jj = pi[tl * 3 + s];
            TOP3_INS(d, jj, d0, d1, d2, i0, i1, i2);
        }
        float w0 = 1.0f / fmaxf(d0, 1e-16f);
        float w1 = 1.0f / fmaxf(d1, 1e-16f);
        float w2 = 1.0f / fmaxf(d2, 1e-16f);
        float inv = 1.0f / (w0 + w1 + w2);
        idxw[m * 3 + 0] = i0;  wgt[m * 3 + 0] = w0 * inv;
        idxw[m * 3 + 1] = i1;  wgt[m * 3 + 1] = w1 * inv;
        idxw[m * 3 + 2] = i2;  wgt[m * 3 + 2] = w2 * inv;
    }
}

// ---- kernel 3: Gb = bf16( xb @ Bt1a^T ). 16384 x 256, K=256.
// B staged in block-shared LDS k-slices.
#define GW_STRIDE 72
__global__ __launch_bounds__(256) void gemm_G(const ushort* __restrict__ A,
                                              const ushort* __restrict__ Bt,
                                              ushort* __restrict__ Gb) {
    __shared__ ushort wB[256 * GW_STRIDE];             // 36 KB
    int tid = threadIdx.x;
    int wave = tid >> 6, lane = tid & 63;
    int m0 = blockIdx.x * 64 + wave * 16;
    int lrow = lane & 15;
    int ko = (lane >> 4) * 8;

    floatx4 acc[16];
#pragma unroll
    for (int i = 0; i < 16; ++i) acc[i] = (floatx4){0.f, 0.f, 0.f, 0.f};

    for (int s = 0; s < 4; ++s) {
        if (s) __syncthreads();
        for (int cch = tid; cch < 2048; cch += 256) {
            int n = cch >> 3, koff = (cch & 7) * 8;
            *(short8*)&wB[n * GW_STRIDE + koff] = *(const short8*)(Bt + n * 256 + s * 64 + koff);
        }
        __syncthreads();
        const ushort* ar = A + (size_t)(m0 + lrow) * 256 + s * 64 + ko;
#pragma unroll
        for (int k0 = 0; k0 < 64; k0 += 32) {
            short8 af = *(const short8*)(ar + k0);
#pragma unroll
            for (int nt = 0; nt < 16; ++nt) {
                short8 bf = *(const short8*)&wB[(nt * 16 + lrow) * GW_STRIDE + k0 + ko];
                acc[nt] = __builtin_amdgcn_mfma_f32_16x16x32_bf16(af, bf, acc[nt], 0, 0, 0);
            }
        }
    }
    int rbase = (lane >> 4) * 4;
#pragma unroll
    for (int nt = 0; nt < 16; ++nt) {
        int n = nt * 16 + lrow;
#pragma unroll
        for (int r = 0; r < 4; ++r)
            Gb[(size_t)(m0 + rbase + r) * 256 + n] = f2bf(acc[nt][r]);
    }
}

// ---- kernel 4: fused  h1 = relu(x_skip@W1b + interp(Gb) + b1);  out = relu(h1@W2 + b2)
#define LDS_STRIDE 264
#define WB_STRIDE 72
__global__ __launch_bounds__(256) void fused_kernel(const ushort* __restrict__ xsb,
                                                    const ushort* __restrict__ Bt1b,
                                                    const ushort* __restrict__ Gb,
                                                    const int* __restrict__ idxw,
                                                    const float* __restrict__ wgt,
                                                    const float* __restrict__ b1,
                                                    const ushort* __restrict__ Bt2,
                                                    const float* __restrict__ b2,
                                                    float* __restrict__ out) {
    __shared__ ushort h1t[4][16 * LDS_STRIDE];     // 33792 B
    __shared__ ushort wB[256 * WB_STRIDE];         // 36864 B
    __shared__ int   sIdx[4][48];
    __shared__ float sWgt[4][48];                  // total ~72 KB -> 2 blk/CU
    int tid = threadIdx.x;
    int wave = tid >> 6, lane = tid & 63;
    int m0 = blockIdx.x * 64 + wave * 16;
    int lrow = lane & 15;
    int ko = (lane >> 4) * 8;
    int rbase = (lane >> 4) * 4;

    if (lane < 48) {
        sIdx[wave][lane] = idxw[m0 * 3 + lane];
        sWgt[wave][lane] = wgt[m0 * 3 + lane];
    }

    const ushort4* Gv = (const ushort4*)Gb;
    const int*   si = sIdx[wave];
    const float* sw = sWgt[wave];
    ushort4 g[4][3];
#define GATHER(slot, i) {                                         \
        int a0 = si[(i) * 3 + 0];                                 \
        int a1 = si[(i) * 3 + 1];                                 \
        int a2 = si[(i) * 3 + 2];                                 \
        g[slot][0] = Gv[(size_t)a0 * 64 + lane];                  \
        g[slot][1] = Gv[(size_t)a1 * 64 + lane];                  \
        g[slot][2] = Gv[(size_t)a2 * 64 + lane]; }

    GATHER(0, 0) GATHER(1, 1) GATHER(2, 2) GATHER(3, 3)

    for (int cch = tid; cch < 2048; cch += 256) {
        int n = cch >> 3, koff = (cch & 7) * 8;
        *(short8*)&wB[n * WB_STRIDE + koff] = *(const short8*)(Bt1b + n * 64 + koff);
    }
    __syncthreads();

    floatx4 acc[16];
#pragma unroll
    for (int i = 0; i < 16; ++i) acc[i] = (floatx4){0.f, 0.f, 0.f, 0.f};
    {
        const ushort* arow = xsb + (size_t)(m0 + lrow) * 64 + ko;
#pragma unroll
        for (int k0 = 0; k0 < 64; k0 += 32) {
            short8 af = *(const short8*)(arow + k0);
#pragma unroll
            for (int nt = 0; nt < 16; ++nt) {
                short8 bf = *(const short8*)&wB[(nt * 16 + lrow) * WB_STRIDE + k0 + ko];
                acc[nt] = __builtin_amdgcn_mfma_f32_16x16x32_bf16(af, bf, acc[nt], 0, 0, 0);
            }
        }
    }

    ushort* ht = h1t[wave];
#pragma unroll
    for (int nt = 0; nt < 16; ++nt) {
        int n = nt * 16 + lrow;
#pragma unroll
        for (int r = 0; r < 4; ++r)
            ht[(rbase + r) * LDS_STRIDE + n] = f2bf(acc[nt][r]);
    }

    {
        float4 bv = ((const float4*)b1)[lane];
#define COMBINE(i) {                                              \
        int s = (i) & 3;                                          \
        float w0 = sw[(i) * 3 + 0], w1 = sw[(i) * 3 + 1], w2 = sw[(i) * 3 + 2]; \
        ushort4 sv = *(const ushort4*)(ht + (i) * LDS_STRIDE + 4 * lane); \
        float4 h;                                                 \
        h.x = fmaxf(bf2f(sv.x) + w0 * bf2f(g[s][0].x) + w1 * bf2f(g[s][1].x) + w2 * bf2f(g[s][2].x) + bv.x, 0.f); \
        h.y = fmaxf(bf2f(sv.y) + w0 * bf2f(g[s][0].y) + w1 * bf2f(g[s][1].y) + w2 * bf2f(g[s][2].y) + bv.y, 0.f); \
        h.z = fmaxf(bf2f(sv.z) + w0 * bf2f(g[s][0].z) + w1 * bf2f(g[s][1].z) + w2 * bf2f(g[s][2].z) + bv.z, 0.f); \
        h.w = fmaxf(bf2f(sv.w) + w0 * bf2f(g[s][0].w) + w1 * bf2f(g[s][1].w) + w2 * bf2f(g[s][2].w) + bv.w, 0.f); \
        ushort4 hp;                                               \
        hp.x = f2bf(h.x); hp.y = f2bf(h.y); hp.z = f2bf(h.z); hp.w = f2bf(h.w); \
        *(ushort4*)(ht + (i) * LDS_STRIDE + 4 * lane) = hp; }

#pragma unroll
        for (int i = 0; i < 12; ++i) { COMBINE(i); GATHER(i & 3, i + 4); }
#pragma unroll
        for (int i = 12; i < 16; ++i) { COMBINE(i); }
#undef GATHER
#undef COMBINE
    }

#pragma unroll
    for (int i = 0; i < 16; ++i) acc[i] = (floatx4){0.f, 0.f, 0.f, 0.f};
    for (int s = 0; s < 4; ++s) {
        __syncthreads();
        for (int cch = tid; cch < 2048; cch += 256) {
            int n = cch >> 3, koff = (cch & 7) * 8;
            *(short8*)&wB[n * WB_STRIDE + koff] = *(const short8*)(Bt2 + n * 256 + s * 64 + koff);
        }
        __syncthreads();
        const ushort* ar = ht + lrow * LDS_STRIDE + s * 64 + ko;
#pragma unroll
        for (int k0 = 0; k0 < 64; k0 += 32) {
            short8 af = *(const short8*)(ar + k0);
#pragma unroll
            for (int nt = 0; nt < 16; ++nt) {
                short8 bf = *(const short8*)&wB[(nt * 16 + lrow) * WB_STRIDE + k0 + ko];
                acc[nt] = __builtin_amdgcn_mfma_f32_16x16x32_bf16(af, bf, acc[nt], 0, 0, 0);
            }
        }
    }
#pragma unroll
    for (int nt = 0; nt < 16; ++nt) {
        int n = nt * 16 + lrow;
        float bv2 = b2[n];
#pragma unroll
        for (int r = 0; r < 4; ++r) {
            float v = fmaxf(acc[nt][r] + bv2, 0.f);
            out[(size_t)(m0 + rbase + r) * OUTD + n] = v;
        }
    }
}

extern "C" void kernel_launch(void* const* d_in, const int* in_sizes, int n_in,
                              void* d_out, int out_size, void* d_ws, size_t ws_size,
                              hipStream_t stream) {
    const float* x        = (const float*)d_in[0];
    const float* pos      = (const float*)d_in[1];
    const float* x_skip   = (const float*)d_in[3];
    const float* pos_skip = (const float*)d_in[4];
    const float* W1       = (const float*)d_in[6];
    const float* b1       = (const float*)d_in[7];
    const float* W2       = (const float*)d_in[8];
    const float* b2       = (const float*)d_in[9];

    char* ws = (char*)d_ws;
    size_t off = 0;
    int*    idxw = (int*)(ws + off);    off += (size_t)MTOT * 3 * 4;      //  768 KB
    float*  wgt  = (float*)(ws + off);  off += (size_t)MTOT * 3 * 4;      //  768 KB
    ushort* xb   = (ushort*)(ws + off); off += (size_t)NCTOT * 256 * 2;   //    8 MB
    ushort* xsb  = (ushort*)(ws + off); off += (size_t)MTOT * 64 * 2;     //    8 MB
    ushort* Gb   = (ushort*)(ws + off); off += (size_t)NCTOT * 256 * 2;   //    8 MB
    ushort* Bt1a = (ushort*)(ws + off); off += (size_t)256 * 256 * 2;     //  128 KB
    ushort* Bt1b = (ushort*)(ws + off); off += (size_t)256 * 64 * 2;      //   32 KB
    ushort* Bt2  = (ushort*)(ws + off); off += (size_t)256 * 256 * 2;     //  128 KB
    float4* pos4 = (float4*)(ws + off); off += (size_t)(NCTOT + 8) * 16;  //  256 KB (+8 pad for prefetch)
    float* out = (float*)d_out;

    prep_kernel<<<(PREP_THREADS + 255) / 256, 256, 0, stream>>>(
        x, x_skip, pos, pos_skip, xb, xsb, pos4, out);
    prep_w<<<36, 256, 0, stream>>>(W1, W2, Bt1a, Bt1b, Bt2);
    knn_fused<<<MTOT / 256, 512, 0, stream>>>(pos4, pos_skip, idxw, wgt);
    gemm_G<<<NCTOT / 64, 256, 0, stream>>>(xb, Bt1a, Gb);
    fused_kernel<<<MTOT / 64, 256, 0, stream>>>(xsb, Bt1b, Gb, idxw, wgt, b1, Bt2, b2, out);
}

// Round 7
// 220.505 us; speedup vs baseline: 1.1086x; 1.1086x over previous
//
#include <hip/hip_runtime.h>
#include <hip/hip_bf16.h>

#define BATCH 8
#define NC 2048
#define NF 8192
#define CDIM 256
#define CSKIP 64
#define OUTD 256
#define MTOT (BATCH*NF)   // 65536
#define NCTOT (BATCH*NC)  // 16384
#define KCH 1024          // per-half coarse chunk

typedef __attribute__((ext_vector_type(8))) short short8;
typedef __attribute__((ext_vector_type(4))) float floatx4;

static __device__ __forceinline__ ushort f2bf(float f) {
    union { float f; unsigned u; } v; v.f = f;
    unsigned r = v.u + 0x7fffu + ((v.u >> 16) & 1u);   // RNE
    return (ushort)(r >> 16);
}
static __device__ __forceinline__ float bf2f(ushort u) {
    union { unsigned u; float f; } v; v.u = ((unsigned)u) << 16;
    return v.f;
}

#if defined(__has_builtin) && __has_builtin(__builtin_amdgcn_fmed3f)
#define MED3F(a, b, c) __builtin_amdgcn_fmed3f((a), (b), (c))
#else
static __device__ __forceinline__ float MED3F(float a, float b, float c) {
    return fmaxf(fminf(a, b), fminf(fmaxf(a, b), c));
}
#endif

// branchless strict-< top-3 insert, parametrized state (exact jax top_k tie order
// when fed ascending j)
#define TOP3_INS(d, jj, D0, D1, D2, I0, I1, I2)     \
    {                                               \
        bool c2 = (d) < D2, c1 = (d) < D1, c0 = (d) < D0; \
        I2 = c1 ? I1 : (c2 ? (jj) : I2);            \
        I1 = c0 ? I0 : (c1 ? (jj) : I1);            \
        I0 = c0 ? (jj) : I0;                        \
        D2 = MED3F(D1, D2, (d));                    \
        D1 = MED3F(D0, D1, (d));                    \
        D0 = fminf(D0, (d));                        \
    }

// ---- kernel 1: prep (bf16 casts of x / x_skip, pos padding, tail outputs)
#define SEG0 1048576   // x -> xb bf16 (float4-wide)
#define SEG1 1048576   // x_skip -> xsb bf16
#define SEG5 16384     // pos -> pos4
#define SEG6 (MTOT*3)  // pos_skip -> out tail
#define SEG7 MTOT      // batch ids -> out tail
#define PREP_THREADS (SEG0+SEG1+SEG5+SEG6+SEG7)

__global__ __launch_bounds__(256) void prep_kernel(const float* __restrict__ x,
                                                   const float* __restrict__ x_skip,
                                                   const float* __restrict__ pos,
                                                   const float* __restrict__ pos_skip,
                                                   ushort* __restrict__ xb,
                                                   ushort* __restrict__ xsb,
                                                   float4* __restrict__ pos4,
                                                   float* __restrict__ out) {
    int t = blockIdx.x * 256 + threadIdx.x;
    if (t < SEG0) {
        float4 v = ((const float4*)x)[t];
        ushort4 p; p.x = f2bf(v.x); p.y = f2bf(v.y); p.z = f2bf(v.z); p.w = f2bf(v.w);
        ((ushort4*)xb)[t] = p;
        return;
    }
    t -= SEG0;
    if (t < SEG1) {
        float4 v = ((const float4*)x_skip)[t];
        ushort4 p; p.x = f2bf(v.x); p.y = f2bf(v.y); p.z = f2bf(v.z); p.w = f2bf(v.w);
        ((ushort4*)xsb)[t] = p;
        return;
    }
    t -= SEG1;
    if (t < SEG5) {
        float4 q;
        q.x = pos[t * 3 + 0]; q.y = pos[t * 3 + 1]; q.z = pos[t * 3 + 2]; q.w = 0.f;
        pos4[t] = q;
        return;
    }
    t -= SEG5;
    if (t < SEG6) {
        out[(size_t)MTOT * OUTD + t] = pos_skip[t];
        return;
    }
    t -= SEG6;
    if (t < SEG7) {
        out[(size_t)MTOT * OUTD + (size_t)MTOT * 3 + t] = (float)(t >> 13);
    }
}

// ---- kernel 1b: LDS-tiled weight transpose (coalesced read AND write).
__global__ __launch_bounds__(256) void prep_w(const float* __restrict__ W1,
                                              const float* __restrict__ W2,
                                              ushort* __restrict__ Bt1a,
                                              ushort* __restrict__ Bt1b,
                                              ushort* __restrict__ Bt2) {
    __shared__ ushort tile[64 * 65];
    int bid = blockIdx.x;
    const float* src; ushort* dst; int k0, n0, KD;
    if (bid < 16)      { src = W1;             dst = Bt1a; k0 = (bid >> 2) * 64; n0 = (bid & 3) * 64; KD = 256; }
    else if (bid < 20) { src = W1 + 256 * 256; dst = Bt1b; k0 = 0;               n0 = (bid - 16) * 64; KD = 64; }
    else               { int b2 = bid - 20; src = W2; dst = Bt2; k0 = (b2 >> 2) * 64; n0 = (b2 & 3) * 64; KD = 256; }
    int tx = threadIdx.x & 63, ty = threadIdx.x >> 6;
#pragma unroll
    for (int r = 0; r < 64; r += 4) {
        int k = r + ty;
        tile[k * 65 + tx] = f2bf(src[(size_t)(k0 + k) * 256 + n0 + tx]);
    }
    __syncthreads();
#pragma unroll
    for (int r = 0; r < 64; r += 4) {
        int n = r + ty;
        dst[(size_t)(n0 + n) * KD + k0 + tx] = tile[tx * 65 + n];
    }
}

// ---- kernel 2: fused 2-way-chunk kNN (r2 structure) + register ping-pong
// prefetch of the LDS windows.
// Cross-round synthesis: VALU busy-TIME is ~41-42us for every delivery
// mechanism (LDS r2 / flat-VMEM r3 / SMEM r6); only the stall component
// differs (23 / 40 / 43 us). r2's rolled loop loads a window and uses it
// immediately -> per-window lgkmcnt stall that 2 waves/SIMD can't hide.
// Fix: 2-window unroll; while window A computes (pure-VALU, ~200cy), window
// B's 6 ds_read_b128 are in flight, and vice versa -> LDS latency hidden,
// no v_mov shuffling (ping-pong registers). LDS arrays padded +8 so the
// final prefetch needs no tail guard (pad values are loaded but the loop
// exits before they are consumed). Distance math, guard, ascending-j insert
// order, and merge are source-identical to round 2 (passed, 64.6us).
__global__ __launch_bounds__(512) void knn_fused(const float4* __restrict__ pos4,
                                                 const float* __restrict__ pos_skip,
                                                 int* __restrict__ idxw,
                                                 float* __restrict__ wgt) {
    __shared__ float sx[NC + 8], sy[NC + 8], sz[NC + 8];   // ~24.1 KB
    __shared__ float pd[256 * 3];              // 3 KB
    __shared__ int   pi[256 * 3];              // 3 KB
    int tid = threadIdx.x;
    int half = tid >> 8;            // 0: coarse [0,1024), 1: [1024,2048)
    int tl = tid & 255;
    int m = blockIdx.x * 256 + tl;
    int b = m >> 13;                // whole block inside one cloud
    int jbase = b * NC;

    for (int i = tid; i < NC; i += 512) {
        float4 q = pos4[jbase + i];
        sx[i] = q.x; sy[i] = q.y; sz[i] = q.z;
    }
    float px = pos_skip[m * 3 + 0];
    float py = pos_skip[m * 3 + 1];
    float pz = pos_skip[m * 3 + 2];
    __syncthreads();

    int joff = half * KCH;

    float d0 = 1e30f, d1 = 1e30f, d2 = 1e30f;
    int i0 = jbase, i1 = jbase, i2 = jbase;

    // preload window 0 (local j 0..7) into A registers
    float4 ax0 = *(const float4*)&sx[joff],     ax1 = *(const float4*)&sx[joff + 4];
    float4 ay0 = *(const float4*)&sy[joff],     ay1 = *(const float4*)&sy[joff + 4];
    float4 az0 = *(const float4*)&sz[joff],     az1 = *(const float4*)&sz[joff + 4];

    for (int j16 = 0; j16 < KCH; j16 += 16) {
        // issue prefetch of window B (local j16+8 .. j16+15)
        int jb2 = joff + j16 + 8;
        float4 bx0 = *(const float4*)&sx[jb2],     bx1 = *(const float4*)&sx[jb2 + 4];
        float4 by0 = *(const float4*)&sy[jb2],     by1 = *(const float4*)&sy[jb2 + 4];
        float4 bz0 = *(const float4*)&sz[jb2],     bz1 = *(const float4*)&sz[jb2 + 4];

        // compute + insert window A (j16 .. j16+7) — hides B's LDS latency
        {
            float dd[8];
#pragma unroll
            for (int u = 0; u < 4; ++u) {
                float ax = px - ax0[u], ay = py - ay0[u], az = pz - az0[u];
                dd[u] = ax * ax + ay * ay + az * az;
                float bx = px - ax1[u], by = py - ay1[u], bz = pz - az1[u];
                dd[u + 4] = bx * bx + by * by + bz * bz;
            }
#pragma unroll
            for (int u = 0; u < 8; ++u) {
                if (__any(dd[u] < d2)) {
                    int jj = jbase + joff + j16 + u;
                    TOP3_INS(dd[u], jj, d0, d1, d2, i0, i1, i2);
                }
            }
        }

        // issue prefetch of next window A (local j16+16 .. j16+23).
        // Last iteration reads into the +8 pad (half==1) or the other
        // half's data (half==0); loop exits before these are consumed.
        int jn = joff + j16 + 16;
        ax0 = *(const float4*)&sx[jn];     ax1 = *(const float4*)&sx[jn + 4];
        ay0 = *(const float4*)&sy[jn];     ay1 = *(const float4*)&sy[jn + 4];
        az0 = *(const float4*)&sz[jn];     az1 = *(const float4*)&sz[jn + 4];

        // compute + insert window B (j16+8 .. j16+15)
        {
            float dd[8];
#pragma unroll
            for (int u = 0; u < 4; ++u) {
                float ax = px - bx0[u], ay = py - by0[u], az = pz - bz0[u];
                dd[u] = ax * ax + ay * ay + az * az;
                float bx = px - bx1[u], by = py - by1[u], bz = pz - bz1[u];
                dd[u + 4] = bx * bx + by * by + bz * bz;
            }
#pragma unroll
            for (int u = 0; u < 8; ++u) {
                if (__any(dd[u] < d2)) {
                    int jj = jbase + joff + j16 + 8 + u;
                    TOP3_INS(dd[u], jj, d0, d1, d2, i0, i1, i2);
                }
            }
        }
    }

    if (half) {
        pd[tl * 3 + 0] = d0; pd[tl * 3 + 1] = d1; pd[tl * 3 + 2] = d2;
        pi[tl * 3 + 0] = i0; pi[tl * 3 + 1] = i1; pi[tl * 3 + 2] = i2;
    }
    __syncthreads();
    if (!half) {
        // merge half-1 partials in ascending-distance order (ties: lower j
        // first inside each half; all half-0 j < half-1 j) -> jax order.
#pragma unroll
        for (int s = 0; s < 3; ++s) {
            float d = pd[tl * 3 + s];
            int jj = pi[tl * 3 + s];
            TOP3_INS(d, jj, d0, d1, d2, i0, i1, i2);
        }
        float w0 = 1.0f / fmaxf(d0, 1e-16f);
        float w1 = 1.0f / fmaxf(d1, 1e-16f);
        float w2 = 1.0f / fmaxf(d2, 1e-16f);
        float inv = 1.0f / (w0 + w1 + w2);
        idxw[m * 3 + 0] = i0;  wgt[m * 3 + 0] = w0 * inv;
        idxw[m * 3 + 1] = i1;  wgt[m * 3 + 1] = w1 * inv;
        idxw[m * 3 + 2] = i2;  wgt[m * 3 + 2] = w2 * inv;
    }
}

// ---- kernel 3: Gb = bf16( xb @ Bt1a^T ). 16384 x 256, K=256.
// B staged in block-shared LDS k-slices.
#define GW_STRIDE 72
__global__ __launch_bounds__(256) void gemm_G(const ushort* __restrict__ A,
                                              const ushort* __restrict__ Bt,
                                              ushort* __restrict__ Gb) {
    __shared__ ushort wB[256 * GW_STRIDE];             // 36 KB
    int tid = threadIdx.x;
    int wave = tid >> 6, lane = tid & 63;
    int m0 = blockIdx.x * 64 + wave * 16;
    int lrow = lane & 15;
    int ko = (lane >> 4) * 8;

    floatx4 acc[16];
#pragma unroll
    for (int i = 0; i < 16; ++i) acc[i] = (floatx4){0.f, 0.f, 0.f, 0.f};

    for (int s = 0; s < 4; ++s) {
        if (s) __syncthreads();
        for (int cch = tid; cch < 2048; cch += 256) {
            int n = cch >> 3, koff = (cch & 7) * 8;
            *(short8*)&wB[n * GW_STRIDE + koff] = *(const short8*)(Bt + n * 256 + s * 64 + koff);
        }
        __syncthreads();
        const ushort* ar = A + (size_t)(m0 + lrow) * 256 + s * 64 + ko;
#pragma unroll
        for (int k0 = 0; k0 < 64; k0 += 32) {
            short8 af = *(const short8*)(ar + k0);
#pragma unroll
            for (int nt = 0; nt < 16; ++nt) {
                short8 bf = *(const short8*)&wB[(nt * 16 + lrow) * GW_STRIDE + k0 + ko];
                acc[nt] = __builtin_amdgcn_mfma_f32_16x16x32_bf16(af, bf, acc[nt], 0, 0, 0);
            }
        }
    }
    int rbase = (lane >> 4) * 4;
#pragma unroll
    for (int nt = 0; nt < 16; ++nt) {
        int n = nt * 16 + lrow;
#pragma unroll
        for (int r = 0; r < 4; ++r)
            Gb[(size_t)(m0 + rbase + r) * 256 + n] = f2bf(acc[nt][r]);
    }
}

// ---- kernel 4: fused  h1 = relu(x_skip@W1b + interp(Gb) + b1);  out = relu(h1@W2 + b2)
#define LDS_STRIDE 264
#define WB_STRIDE 72
__global__ __launch_bounds__(256) void fused_kernel(const ushort* __restrict__ xsb,
                                                    const ushort* __restrict__ Bt1b,
                                                    const ushort* __restrict__ Gb,
                                                    const int* __restrict__ idxw,
                                                    const float* __restrict__ wgt,
                                                    const float* __restrict__ b1,
                                                    const ushort* __restrict__ Bt2,
                                                    const float* __restrict__ b2,
                                                    float* __restrict__ out) {
    __shared__ ushort h1t[4][16 * LDS_STRIDE];     // 33792 B
    __shared__ ushort wB[256 * WB_STRIDE];         // 36864 B
    __shared__ int   sIdx[4][48];
    __shared__ float sWgt[4][48];                  // total ~72 KB -> 2 blk/CU
    int tid = threadIdx.x;
    int wave = tid >> 6, lane = tid & 63;
    int m0 = blockIdx.x * 64 + wave * 16;
    int lrow = lane & 15;
    int ko = (lane >> 4) * 8;
    int rbase = (lane >> 4) * 4;

    if (lane < 48) {
        sIdx[wave][lane] = idxw[m0 * 3 + lane];
        sWgt[wave][lane] = wgt[m0 * 3 + lane];
    }

    const ushort4* Gv = (const ushort4*)Gb;
    const int*   si = sIdx[wave];
    const float* sw = sWgt[wave];
    ushort4 g[4][3];
#define GATHER(slot, i) {                                         \
        int a0 = si[(i) * 3 + 0];                                 \
        int a1 = si[(i) * 3 + 1];                                 \
        int a2 = si[(i) * 3 + 2];                                 \
        g[slot][0] = Gv[(size_t)a0 * 64 + lane];                  \
        g[slot][1] = Gv[(size_t)a1 * 64 + lane];                  \
        g[slot][2] = Gv[(size_t)a2 * 64 + lane]; }

    GATHER(0, 0) GATHER(1, 1) GATHER(2, 2) GATHER(3, 3)

    for (int cch = tid; cch < 2048; cch += 256) {
        int n = cch >> 3, koff = (cch & 7) * 8;
        *(short8*)&wB[n * WB_STRIDE + koff] = *(const short8*)(Bt1b + n * 64 + koff);
    }
    __syncthreads();

    floatx4 acc[16];
#pragma unroll
    for (int i = 0; i < 16; ++i) acc[i] = (floatx4){0.f, 0.f, 0.f, 0.f};
    {
        const ushort* arow = xsb + (size_t)(m0 + lrow) * 64 + ko;
#pragma unroll
        for (int k0 = 0; k0 < 64; k0 += 32) {
            short8 af = *(const short8*)(arow + k0);
#pragma unroll
            for (int nt = 0; nt < 16; ++nt) {
                short8 bf = *(const short8*)&wB[(nt * 16 + lrow) * WB_STRIDE + k0 + ko];
                acc[nt] = __builtin_amdgcn_mfma_f32_16x16x32_bf16(af, bf, acc[nt], 0, 0, 0);
            }
        }
    }

    ushort* ht = h1t[wave];
#pragma unroll
    for (int nt = 0; nt < 16; ++nt) {
        int n = nt * 16 + lrow;
#pragma unroll
        for (int r = 0; r < 4; ++r)
            ht[(rbase + r) * LDS_STRIDE + n] = f2bf(acc[nt][r]);
    }

    {
        float4 bv = ((const float4*)b1)[lane];
#define COMBINE(i) {                                              \
        int s = (i) & 3;                                          \
        float w0 = sw[(i) * 3 + 0], w1 = sw[(i) * 3 + 1], w2 = sw[(i) * 3 + 2]; \
        ushort4 sv = *(const ushort4*)(ht + (i) * LDS_STRIDE + 4 * lane); \
        float4 h;                                                 \
        h.x = fmaxf(bf2f(sv.x) + w0 * bf2f(g[s][0].x) + w1 * bf2f(g[s][1].x) + w2 * bf2f(g[s][2].x) + bv.x, 0.f); \
        h.y = fmaxf(bf2f(sv.y) + w0 * bf2f(g[s][0].y) + w1 * bf2f(g[s][1].y) + w2 * bf2f(g[s][2].y) + bv.y, 0.f); \
        h.z = fmaxf(bf2f(sv.z) + w0 * bf2f(g[s][0].z) + w1 * bf2f(g[s][1].z) + w2 * bf2f(g[s][2].z) + bv.z, 0.f); \
        h.w = fmaxf(bf2f(sv.w) + w0 * bf2f(g[s][0].w) + w1 * bf2f(g[s][1].w) + w2 * bf2f(g[s][2].w) + bv.w, 0.f); \
        ushort4 hp;                                               \
        hp.x = f2bf(h.x); hp.y = f2bf(h.y); hp.z = f2bf(h.z); hp.w = f2bf(h.w); \
        *(ushort4*)(ht + (i) * LDS_STRIDE + 4 * lane) = hp; }

#pragma unroll
        for (int i = 0; i < 12; ++i) { COMBINE(i); GATHER(i & 3, i + 4); }
#pragma unroll
        for (int i = 12; i < 16; ++i) { COMBINE(i); }
#undef GATHER
#undef COMBINE
    }

#pragma unroll
    for (int i = 0; i < 16; ++i) acc[i] = (floatx4){0.f, 0.f, 0.f, 0.f};
    for (int s = 0; s < 4; ++s) {
        __syncthreads();
        for (int cch = tid; cch < 2048; cch += 256) {
            int n = cch >> 3, koff = (cch & 7) * 8;
            *(short8*)&wB[n * WB_STRIDE + koff] = *(const short8*)(Bt2 + n * 256 + s * 64 + koff);
        }
        __syncthreads();
        const ushort* ar = ht + lrow * LDS_STRIDE + s * 64 + ko;
#pragma unroll
        for (int k0 = 0; k0 < 64; k0 += 32) {
            short8 af = *(const short8*)(ar + k0);
#pragma unroll
            for (int nt = 0; nt < 16; ++nt) {
                short8 bf = *(const short8*)&wB[(nt * 16 + lrow) * WB_STRIDE + k0 + ko];
                acc[nt] = __builtin_amdgcn_mfma_f32_16x16x32_bf16(af, bf, acc[nt], 0, 0, 0);
            }
        }
    }
#pragma unroll
    for (int nt = 0; nt < 16; ++nt) {
        int n = nt * 16 + lrow;
        float bv2 = b2[n];
#pragma unroll
        for (int r = 0; r < 4; ++r) {
            float v = fmaxf(acc[nt][r] + bv2, 0.f);
            out[(size_t)(m0 + rbase + r) * OUTD + n] = v;
        }
    }
}

extern "C" void kernel_launch(void* const* d_in, const int* in_sizes, int n_in,
                              void* d_out, int out_size, void* d_ws, size_t ws_size,
                              hipStream_t stream) {
    const float* x        = (const float*)d_in[0];
    const float* pos      = (const float*)d_in[1];
    const float* x_skip   = (const float*)d_in[3];
    const float* pos_skip = (const float*)d_in[4];
    const float* W1       = (const float*)d_in[6];
    const float* b1       = (const float*)d_in[7];
    const float* W2       = (const float*)d_in[8];
    const float* b2       = (const float*)d_in[9];

    char* ws = (char*)d_ws;
    size_t off = 0;
    int*    idxw = (int*)(ws + off);    off += (size_t)MTOT * 3 * 4;      //  768 KB
    float*  wgt  = (float*)(ws + off);  off += (size_t)MTOT * 3 * 4;      //  768 KB
    ushort* xb   = (ushort*)(ws + off); off += (size_t)NCTOT * 256 * 2;   //    8 MB
    ushort* xsb  = (ushort*)(ws + off); off += (size_t)MTOT * 64 * 2;     //    8 MB
    ushort* Gb   = (ushort*)(ws + off); off += (size_t)NCTOT * 256 * 2;   //    8 MB
    ushort* Bt1a = (ushort*)(ws + off); off += (size_t)256 * 256 * 2;     //  128 KB
    ushort* Bt1b = (ushort*)(ws + off); off += (size_t)256 * 64 * 2;      //   32 KB
    ushort* Bt2  = (ushort*)(ws + off); off += (size_t)256 * 256 * 2;     //  128 KB
    float4* pos4 = (float4*)(ws + off); off += (size_t)(NCTOT + 8) * 16;  //  256 KB
    float* out = (float*)d_out;

    prep_kernel<<<(PREP_THREADS + 255) / 256, 256, 0, stream>>>(
        x, x_skip, pos, pos_skip, xb, xsb, pos4, out);
    prep_w<<<36, 256, 0, stream>>>(W1, W2, Bt1a, Bt1b, Bt2);
    knn_fused<<<MTOT / 256, 512, 0, stream>>>(pos4, pos_skip, idxw, wgt);
    gemm_G<<<NCTOT / 64, 256, 0, stream>>>(xb, Bt1a, Gb);
    fused_kernel<<<MTOT / 64, 256, 0, stream>>>(xsb, Bt1b, Gb, idxw, wgt, b1, Bt2, b2, out);
}

// Round 8
// 214.841 us; speedup vs baseline: 1.1378x; 1.0264x over previous
//
#include <hip/hip_runtime.h>
#include <hip/hip_bf16.h>

#define BATCH 8
#define NC 2048
#define NF 8192
#define CDIM 256
#define CSKIP 64
#define OUTD 256
#define MTOT (BATCH*NF)   // 65536
#define NCTOT (BATCH*NC)  // 16384
#define KCH4 512          // per-wave coarse chunk (4-way split)

typedef __attribute__((ext_vector_type(8))) short short8;
typedef __attribute__((ext_vector_type(4))) float floatx4;

static __device__ __forceinline__ ushort f2bf(float f) {
    union { float f; unsigned u; } v; v.f = f;
    unsigned r = v.u + 0x7fffu + ((v.u >> 16) & 1u);   // RNE
    return (ushort)(r >> 16);
}
static __device__ __forceinline__ float bf2f(ushort u) {
    union { unsigned u; float f; } v; v.u = ((unsigned)u) << 16;
    return v.f;
}

#if defined(__has_builtin) && __has_builtin(__builtin_amdgcn_fmed3f)
#define MED3F(a, b, c) __builtin_amdgcn_fmed3f((a), (b), (c))
#else
static __device__ __forceinline__ float MED3F(float a, float b, float c) {
    return fmaxf(fminf(a, b), fminf(fmaxf(a, b), c));
}
#endif

// branchless strict-< top-3 insert, parametrized state (exact jax top_k tie order
// when fed ascending j)
#define TOP3_INS(d, jj, D0, D1, D2, I0, I1, I2)     \
    {                                               \
        bool c2 = (d) < D2, c1 = (d) < D1, c0 = (d) < D0; \
        I2 = c1 ? I1 : (c2 ? (jj) : I2);            \
        I1 = c0 ? I0 : (c1 ? (jj) : I1);            \
        I0 = c0 ? (jj) : I0;                        \
        D2 = MED3F(D1, D2, (d));                    \
        D1 = MED3F(D0, D1, (d));                    \
        D0 = fminf(D0, (d));                        \
    }

// ---- kernel 1: prep (bf16 casts of x / x_skip, pos padding, tail outputs)
#define SEG0 1048576   // x -> xb bf16 (float4-wide)
#define SEG1 1048576   // x_skip -> xsb bf16
#define SEG5 16384     // pos -> pos4
#define SEG6 (MTOT*3)  // pos_skip -> out tail
#define SEG7 MTOT      // batch ids -> out tail
#define PREP_THREADS (SEG0+SEG1+SEG5+SEG6+SEG7)

__global__ __launch_bounds__(256) void prep_kernel(const float* __restrict__ x,
                                                   const float* __restrict__ x_skip,
                                                   const float* __restrict__ pos,
                                                   const float* __restrict__ pos_skip,
                                                   ushort* __restrict__ xb,
                                                   ushort* __restrict__ xsb,
                                                   float4* __restrict__ pos4,
                                                   float* __restrict__ out) {
    int t = blockIdx.x * 256 + threadIdx.x;
    if (t < SEG0) {
        float4 v = ((const float4*)x)[t];
        ushort4 p; p.x = f2bf(v.x); p.y = f2bf(v.y); p.z = f2bf(v.z); p.w = f2bf(v.w);
        ((ushort4*)xb)[t] = p;
        return;
    }
    t -= SEG0;
    if (t < SEG1) {
        float4 v = ((const float4*)x_skip)[t];
        ushort4 p; p.x = f2bf(v.x); p.y = f2bf(v.y); p.z = f2bf(v.z); p.w = f2bf(v.w);
        ((ushort4*)xsb)[t] = p;
        return;
    }
    t -= SEG1;
    if (t < SEG5) {
        float4 q;
        q.x = pos[t * 3 + 0]; q.y = pos[t * 3 + 1]; q.z = pos[t * 3 + 2]; q.w = 0.f;
        pos4[t] = q;
        return;
    }
    t -= SEG5;
    if (t < SEG6) {
        out[(size_t)MTOT * OUTD + t] = pos_skip[t];
        return;
    }
    t -= SEG6;
    if (t < SEG7) {
        out[(size_t)MTOT * OUTD + (size_t)MTOT * 3 + t] = (float)(t >> 13);
    }
}

// ---- kernel 1b: LDS-tiled weight transpose (coalesced read AND write).
__global__ __launch_bounds__(256) void prep_w(const float* __restrict__ W1,
                                              const float* __restrict__ W2,
                                              ushort* __restrict__ Bt1a,
                                              ushort* __restrict__ Bt1b,
                                              ushort* __restrict__ Bt2) {
    __shared__ ushort tile[64 * 65];
    int bid = blockIdx.x;
    const float* src; ushort* dst; int k0, n0, KD;
    if (bid < 16)      { src = W1;             dst = Bt1a; k0 = (bid >> 2) * 64; n0 = (bid & 3) * 64; KD = 256; }
    else if (bid < 20) { src = W1 + 256 * 256; dst = Bt1b; k0 = 0;               n0 = (bid - 16) * 64; KD = 64; }
    else               { int b2 = bid - 20; src = W2; dst = Bt2; k0 = (b2 >> 2) * 64; n0 = (b2 & 3) * 64; KD = 256; }
    int tx = threadIdx.x & 63, ty = threadIdx.x >> 6;
#pragma unroll
    for (int r = 0; r < 64; r += 4) {
        int k = r + ty;
        tile[k * 65 + tx] = f2bf(src[(size_t)(k0 + k) * 256 + n0 + tx]);
    }
    __syncthreads();
#pragma unroll
    for (int r = 0; r < 64; r += 4) {
        int n = r + ty;
        dst[(size_t)(n0 + n) * KD + k0 + tx] = tile[tx * 65 + n];
    }
}

// ---- kernel 2: 4-way-chunk kNN, 256-thr blocks, 4 waves/SIMD.
// Round-7 synthesis: at 2 waves/SIMD neither pipe saturates (VALU 69%,
// LDS 50% by corrected per-CU accounting) — the limit is issue/branch-shadow
// ILP of the guarded inserts. Fix TLP, not the loop: block = 256 thr owning
// 64 fine pts (m = blockIdx*64+lane); wave w scans chunk [w*512,(w+1)*512)
// with the r7 ping-pong inner loop verbatim (KCH->512); waves 1-3 write
// top-3 partials to LDS; wave 0 merges in chunk order (identical ascending-j
// tie semantics to the proven 8-chunk knn_merge). Grid = 1024 blocks,
// ~29.3 KB LDS -> 4 blocks/CU = 16 waves/CU = 4 waves/SIMD (2x current).
// Staging is 4x redundant per CU but pos4 is L2-resident (256 KB).
__global__ __launch_bounds__(256) void knn_fused(const float4* __restrict__ pos4,
                                                 const float* __restrict__ pos_skip,
                                                 int* __restrict__ idxw,
                                                 float* __restrict__ wgt) {
    __shared__ float sx[NC + 8], sy[NC + 8], sz[NC + 8];   // ~24.1 KB
    __shared__ float pd[3][64 * 3];            // 2.25 KB
    __shared__ int   pi[3][64 * 3];            // 2.25 KB
    int tid = threadIdx.x;
    int wave = tid >> 6;            // chunk index 0..3
    int lane = tid & 63;
    int m = blockIdx.x * 64 + lane; // all 4 waves: same 64 fine points
    int b = m >> 13;                // whole block inside one cloud
    int jbase = b * NC;

    for (int i = tid; i < NC; i += 256) {
        float4 q = pos4[jbase + i];
        sx[i] = q.x; sy[i] = q.y; sz[i] = q.z;
    }
    float px = pos_skip[m * 3 + 0];
    float py = pos_skip[m * 3 + 1];
    float pz = pos_skip[m * 3 + 2];
    __syncthreads();

    int joff = wave * KCH4;

    float d0 = 1e30f, d1 = 1e30f, d2 = 1e30f;
    int i0 = jbase, i1 = jbase, i2 = jbase;

    // preload window 0 (local j 0..7) into A registers
    float4 ax0 = *(const float4*)&sx[joff],     ax1 = *(const float4*)&sx[joff + 4];
    float4 ay0 = *(const float4*)&sy[joff],     ay1 = *(const float4*)&sy[joff + 4];
    float4 az0 = *(const float4*)&sz[joff],     az1 = *(const float4*)&sz[joff + 4];

    for (int j16 = 0; j16 < KCH4; j16 += 16) {
        // issue prefetch of window B (local j16+8 .. j16+15)
        int jb2 = joff + j16 + 8;
        float4 bx0 = *(const float4*)&sx[jb2],     bx1 = *(const float4*)&sx[jb2 + 4];
        float4 by0 = *(const float4*)&sy[jb2],     by1 = *(const float4*)&sy[jb2 + 4];
        float4 bz0 = *(const float4*)&sz[jb2],     bz1 = *(const float4*)&sz[jb2 + 4];

        // compute + insert window A (j16 .. j16+7) — hides B's LDS latency
        {
            float dd[8];
#pragma unroll
            for (int u = 0; u < 4; ++u) {
                float ax = px - ax0[u], ay = py - ay0[u], az = pz - az0[u];
                dd[u] = ax * ax + ay * ay + az * az;
                float bx = px - ax1[u], by = py - ay1[u], bz = pz - az1[u];
                dd[u + 4] = bx * bx + by * by + bz * bz;
            }
#pragma unroll
            for (int u = 0; u < 8; ++u) {
                if (__any(dd[u] < d2)) {
                    int jj = jbase + joff + j16 + u;
                    TOP3_INS(dd[u], jj, d0, d1, d2, i0, i1, i2);
                }
            }
        }

        // issue prefetch of next window A (local j16+16 .. j16+23).
        // Last iteration of wave 3 reads into the +8 pad; values are dead
        // (loop exits before consumption).
        int jn = joff + j16 + 16;
        ax0 = *(const float4*)&sx[jn];     ax1 = *(const float4*)&sx[jn + 4];
        ay0 = *(const float4*)&sy[jn];     ay1 = *(const float4*)&sy[jn + 4];
        az0 = *(const float4*)&sz[jn];     az1 = *(const float4*)&sz[jn + 4];

        // compute + insert window B (j16+8 .. j16+15)
        {
            float dd[8];
#pragma unroll
            for (int u = 0; u < 4; ++u) {
                float ax = px - bx0[u], ay = py - by0[u], az = pz - bz0[u];
                dd[u] = ax * ax + ay * ay + az * az;
                float bx = px - bx1[u], by = py - by1[u], bz = pz - bz1[u];
                dd[u + 4] = bx * bx + by * by + bz * bz;
            }
#pragma unroll
            for (int u = 0; u < 8; ++u) {
                if (__any(dd[u] < d2)) {
                    int jj = jbase + joff + j16 + 8 + u;
                    TOP3_INS(dd[u], jj, d0, d1, d2, i0, i1, i2);
                }
            }
        }
    }

    if (wave) {
        pd[wave - 1][lane * 3 + 0] = d0; pd[wave - 1][lane * 3 + 1] = d1; pd[wave - 1][lane * 3 + 2] = d2;
        pi[wave - 1][lane * 3 + 0] = i0; pi[wave - 1][lane * 3 + 1] = i1; pi[wave - 1][lane * 3 + 2] = i2;
    }
    __syncthreads();
    if (wave == 0) {
        // merge chunk 1..3 partials in chunk order (all chunk-c j < chunk-c+1
        // j; within-partial d0<=d1<=d2 with ascending-j ties) -> identical to
        // the proven knn_merge semantics -> jax top_k order.
#pragma unroll
        for (int c = 0; c < 3; ++c) {
#pragma unroll
            for (int s = 0; s < 3; ++s) {
                float d = pd[c][lane * 3 + s];
                int jj = pi[c][lane * 3 + s];
                TOP3_INS(d, jj, d0, d1, d2, i0, i1, i2);
            }
        }
        float w0 = 1.0f / fmaxf(d0, 1e-16f);
        float w1 = 1.0f / fmaxf(d1, 1e-16f);
        float w2 = 1.0f / fmaxf(d2, 1e-16f);
        float inv = 1.0f / (w0 + w1 + w2);
        idxw[m * 3 + 0] = i0;  wgt[m * 3 + 0] = w0 * inv;
        idxw[m * 3 + 1] = i1;  wgt[m * 3 + 1] = w1 * inv;
        idxw[m * 3 + 2] = i2;  wgt[m * 3 + 2] = w2 * inv;
    }
}

// ---- kernel 3: Gb = bf16( xb @ Bt1a^T ). 16384 x 256, K=256.
// B staged in block-shared LDS k-slices.
#define GW_STRIDE 72
__global__ __launch_bounds__(256) void gemm_G(const ushort* __restrict__ A,
                                              const ushort* __restrict__ Bt,
                                              ushort* __restrict__ Gb) {
    __shared__ ushort wB[256 * GW_STRIDE];             // 36 KB
    int tid = threadIdx.x;
    int wave = tid >> 6, lane = tid & 63;
    int m0 = blockIdx.x * 64 + wave * 16;
    int lrow = lane & 15;
    int ko = (lane >> 4) * 8;

    floatx4 acc[16];
#pragma unroll
    for (int i = 0; i < 16; ++i) acc[i] = (floatx4){0.f, 0.f, 0.f, 0.f};

    for (int s = 0; s < 4; ++s) {
        if (s) __syncthreads();
        for (int cch = tid; cch < 2048; cch += 256) {
            int n = cch >> 3, koff = (cch & 7) * 8;
            *(short8*)&wB[n * GW_STRIDE + koff] = *(const short8*)(Bt + n * 256 + s * 64 + koff);
        }
        __syncthreads();
        const ushort* ar = A + (size_t)(m0 + lrow) * 256 + s * 64 + ko;
#pragma unroll
        for (int k0 = 0; k0 < 64; k0 += 32) {
            short8 af = *(const short8*)(ar + k0);
#pragma unroll
            for (int nt = 0; nt < 16; ++nt) {
                short8 bf = *(const short8*)&wB[(nt * 16 + lrow) * GW_STRIDE + k0 + ko];
                acc[nt] = __builtin_amdgcn_mfma_f32_16x16x32_bf16(af, bf, acc[nt], 0, 0, 0);
            }
        }
    }
    int rbase = (lane >> 4) * 4;
#pragma unroll
    for (int nt = 0; nt < 16; ++nt) {
        int n = nt * 16 + lrow;
#pragma unroll
        for (int r = 0; r < 4; ++r)
            Gb[(size_t)(m0 + rbase + r) * 256 + n] = f2bf(acc[nt][r]);
    }
}

// ---- kernel 4: fused  h1 = relu(x_skip@W1b + interp(Gb) + b1);  out = relu(h1@W2 + b2)
#define LDS_STRIDE 264
#define WB_STRIDE 72
__global__ __launch_bounds__(256) void fused_kernel(const ushort* __restrict__ xsb,
                                                    const ushort* __restrict__ Bt1b,
                                                    const ushort* __restrict__ Gb,
                                                    const int* __restrict__ idxw,
                                                    const float* __restrict__ wgt,
                                                    const float* __restrict__ b1,
                                                    const ushort* __restrict__ Bt2,
                                                    const float* __restrict__ b2,
                                                    float* __restrict__ out) {
    __shared__ ushort h1t[4][16 * LDS_STRIDE];     // 33792 B
    __shared__ ushort wB[256 * WB_STRIDE];         // 36864 B
    __shared__ int   sIdx[4][48];
    __shared__ float sWgt[4][48];                  // total ~72 KB -> 2 blk/CU
    int tid = threadIdx.x;
    int wave = tid >> 6, lane = tid & 63;
    int m0 = blockIdx.x * 64 + wave * 16;
    int lrow = lane & 15;
    int ko = (lane >> 4) * 8;
    int rbase = (lane >> 4) * 4;

    if (lane < 48) {
        sIdx[wave][lane] = idxw[m0 * 3 + lane];
        sWgt[wave][lane] = wgt[m0 * 3 + lane];
    }

    const ushort4* Gv = (const ushort4*)Gb;
    const int*   si = sIdx[wave];
    const float* sw = sWgt[wave];
    ushort4 g[4][3];
#define GATHER(slot, i) {                                         \
        int a0 = si[(i) * 3 + 0];                                 \
        int a1 = si[(i) * 3 + 1];                                 \
        int a2 = si[(i) * 3 + 2];                                 \
        g[slot][0] = Gv[(size_t)a0 * 64 + lane];                  \
        g[slot][1] = Gv[(size_t)a1 * 64 + lane];                  \
        g[slot][2] = Gv[(size_t)a2 * 64 + lane]; }

    GATHER(0, 0) GATHER(1, 1) GATHER(2, 2) GATHER(3, 3)

    for (int cch = tid; cch < 2048; cch += 256) {
        int n = cch >> 3, koff = (cch & 7) * 8;
        *(short8*)&wB[n * WB_STRIDE + koff] = *(const short8*)(Bt1b + n * 64 + koff);
    }
    __syncthreads();

    floatx4 acc[16];
#pragma unroll
    for (int i = 0; i < 16; ++i) acc[i] = (floatx4){0.f, 0.f, 0.f, 0.f};
    {
        const ushort* arow = xsb + (size_t)(m0 + lrow) * 64 + ko;
#pragma unroll
        for (int k0 = 0; k0 < 64; k0 += 32) {
            short8 af = *(const short8*)(arow + k0);
#pragma unroll
            for (int nt = 0; nt < 16; ++nt) {
                short8 bf = *(const short8*)&wB[(nt * 16 + lrow) * WB_STRIDE + k0 + ko];
                acc[nt] = __builtin_amdgcn_mfma_f32_16x16x32_bf16(af, bf, acc[nt], 0, 0, 0);
            }
        }
    }

    ushort* ht = h1t[wave];
#pragma unroll
    for (int nt = 0; nt < 16; ++nt) {
        int n = nt * 16 + lrow;
#pragma unroll
        for (int r = 0; r < 4; ++r)
            ht[(rbase + r) * LDS_STRIDE + n] = f2bf(acc[nt][r]);
    }

    {
        float4 bv = ((const float4*)b1)[lane];
#define COMBINE(i) {                                              \
        int s = (i) & 3;                                          \
        float w0 = sw[(i) * 3 + 0], w1 = sw[(i) * 3 + 1], w2 = sw[(i) * 3 + 2]; \
        ushort4 sv = *(const ushort4*)(ht + (i) * LDS_STRIDE + 4 * lane); \
        float4 h;                                                 \
        h.x = fmaxf(bf2f(sv.x) + w0 * bf2f(g[s][0].x) + w1 * bf2f(g[s][1].x) + w2 * bf2f(g[s][2].x) + bv.x, 0.f); \
        h.y = fmaxf(bf2f(sv.y) + w0 * bf2f(g[s][0].y) + w1 * bf2f(g[s][1].y) + w2 * bf2f(g[s][2].y) + bv.y, 0.f); \
        h.z = fmaxf(bf2f(sv.z) + w0 * bf2f(g[s][0].z) + w1 * bf2f(g[s][1].z) + w2 * bf2f(g[s][2].z) + bv.z, 0.f); \
        h.w = fmaxf(bf2f(sv.w) + w0 * bf2f(g[s][0].w) + w1 * bf2f(g[s][1].w) + w2 * bf2f(g[s][2].w) + bv.w, 0.f); \
        ushort4 hp;                                               \
        hp.x = f2bf(h.x); hp.y = f2bf(h.y); hp.z = f2bf(h.z); hp.w = f2bf(h.w); \
        *(ushort4*)(ht + (i) * LDS_STRIDE + 4 * lane) = hp; }

#pragma unroll
        for (int i = 0; i < 12; ++i) { COMBINE(i); GATHER(i & 3, i + 4); }
#pragma unroll
        for (int i = 12; i < 16; ++i) { COMBINE(i); }
#undef GATHER
#undef COMBINE
    }

#pragma unroll
    for (int i = 0; i < 16; ++i) acc[i] = (floatx4){0.f, 0.f, 0.f, 0.f};
    for (int s = 0; s < 4; ++s) {
        __syncthreads();
        for (int cch = tid; cch < 2048; cch += 256) {
            int n = cch >> 3, koff = (cch & 7) * 8;
            *(short8*)&wB[n * WB_STRIDE + koff] = *(const short8*)(Bt2 + n * 256 + s * 64 + koff);
        }
        __syncthreads();
        const ushort* ar = ht + lrow * LDS_STRIDE + s * 64 + ko;
#pragma unroll
        for (int k0 = 0; k0 < 64; k0 += 32) {
            short8 af = *(const short8*)(ar + k0);
#pragma unroll
            for (int nt = 0; nt < 16; ++nt) {
                short8 bf = *(const short8*)&wB[(nt * 16 + lrow) * WB_STRIDE + k0 + ko];
                acc[nt] = __builtin_amdgcn_mfma_f32_16x16x32_bf16(af, bf, acc[nt], 0, 0, 0);
            }
        }
    }
#pragma unroll
    for (int nt = 0; nt < 16; ++nt) {
        int n = nt * 16 + lrow;
        float bv2 = b2[n];
#pragma unroll
        for (int r = 0; r < 4; ++r) {
            float v = fmaxf(acc[nt][r] + bv2, 0.f);
            out[(size_t)(m0 + rbase + r) * OUTD + n] = v;
        }
    }
}

extern "C" void kernel_launch(void* const* d_in, const int* in_sizes, int n_in,
                              void* d_out, int out_size, void* d_ws, size_t ws_size,
                              hipStream_t stream) {
    const float* x        = (const float*)d_in[0];
    const float* pos      = (const float*)d_in[1];
    const float* x_skip   = (const float*)d_in[3];
    const float* pos_skip = (const float*)d_in[4];
    const float* W1       = (const float*)d_in[6];
    const float* b1       = (const float*)d_in[7];
    const float* W2       = (const float*)d_in[8];
    const float* b2       = (const float*)d_in[9];

    char* ws = (char*)d_ws;
    size_t off = 0;
    int*    idxw = (int*)(ws + off);    off += (size_t)MTOT * 3 * 4;      //  768 KB
    float*  wgt  = (float*)(ws + off);  off += (size_t)MTOT * 3 * 4;      //  768 KB
    ushort* xb   = (ushort*)(ws + off); off += (size_t)NCTOT * 256 * 2;   //    8 MB
    ushort* xsb  = (ushort*)(ws + off); off += (size_t)MTOT * 64 * 2;     //    8 MB
    ushort* Gb   = (ushort*)(ws + off); off += (size_t)NCTOT * 256 * 2;   //    8 MB
    ushort* Bt1a = (ushort*)(ws + off); off += (size_t)256 * 256 * 2;     //  128 KB
    ushort* Bt1b = (ushort*)(ws + off); off += (size_t)256 * 64 * 2;      //   32 KB
    ushort* Bt2  = (ushort*)(ws + off); off += (size_t)256 * 256 * 2;     //  128 KB
    float4* pos4 = (float4*)(ws + off); off += (size_t)(NCTOT + 8) * 16;  //  256 KB
    float* out = (float*)d_out;

    prep_kernel<<<(PREP_THREADS + 255) / 256, 256, 0, stream>>>(
        x, x_skip, pos, pos_skip, xb, xsb, pos4, out);
    prep_w<<<36, 256, 0, stream>>>(W1, W2, Bt1a, Bt1b, Bt2);
    knn_fused<<<MTOT / 64, 256, 0, stream>>>(pos4, pos_skip, idxw, wgt);
    gemm_G<<<NCTOT / 64, 256, 0, stream>>>(xb, Bt1a, Gb);
    fused_kernel<<<MTOT / 64, 256, 0, stream>>>(xsb, Bt1b, Gb, idxw, wgt, b1, Bt2, b2, out);
}

// Round 9
// 199.784 us; speedup vs baseline: 1.2236x; 1.0754x over previous
//
#include <hip/hip_runtime.h>
#include <hip/hip_bf16.h>

#define BATCH 8
#define NC 2048
#define NF 8192
#define CDIM 256
#define CSKIP 64
#define OUTD 256
#define MTOT (BATCH*NF)   // 65536
#define NCTOT (BATCH*NC)  // 16384
#define KCH4 512          // per-wave coarse chunk (4-way split)

typedef __attribute__((ext_vector_type(8))) short short8;
typedef __attribute__((ext_vector_type(4))) float floatx4;

static __device__ __forceinline__ ushort f2bf(float f) {
    union { float f; unsigned u; } v; v.f = f;
    unsigned r = v.u + 0x7fffu + ((v.u >> 16) & 1u);   // RNE
    return (ushort)(r >> 16);
}
static __device__ __forceinline__ float bf2f(ushort u) {
    union { unsigned u; float f; } v; v.u = ((unsigned)u) << 16;
    return v.f;
}

#if defined(__has_builtin) && __has_builtin(__builtin_amdgcn_fmed3f)
#define MED3F(a, b, c) __builtin_amdgcn_fmed3f((a), (b), (c))
#else
static __device__ __forceinline__ float MED3F(float a, float b, float c) {
    return fmaxf(fminf(a, b), fminf(fmaxf(a, b), c));
}
#endif

// branchless strict-< top-3 insert, parametrized state (exact jax top_k tie order
// when fed ascending j)
#define TOP3_INS(d, jj, D0, D1, D2, I0, I1, I2)     \
    {                                               \
        bool c2 = (d) < D2, c1 = (d) < D1, c0 = (d) < D0; \
        I2 = c1 ? I1 : (c2 ? (jj) : I2);            \
        I1 = c0 ? I0 : (c1 ? (jj) : I1);            \
        I0 = c0 ? (jj) : I0;                        \
        D2 = MED3F(D1, D2, (d));                    \
        D1 = MED3F(D0, D1, (d));                    \
        D0 = fminf(D0, (d));                        \
    }

// ---- kernel 1: prep_all = prep_w (blocks 0..35) + prep (blocks 36..).
// prep_w and prep touch disjoint data (W1/W2 vs x/x_skip/pos/pos_skip) —
// merging saves a launch. prep_w's 8.3KB LDS is declared by all blocks but
// prep is a streaming kernel; occupancy unaffected at 256-thr blocks.
#define SEG0 1048576   // x -> xb bf16 (float4-wide)
#define SEG1 1048576   // x_skip -> xsb bf16
#define SEG5 16384     // pos -> pos4
#define SEG6 (MTOT*3)  // pos_skip -> out tail
#define SEG7 MTOT      // batch ids -> out tail
#define PREP_THREADS (SEG0+SEG1+SEG5+SEG6+SEG7)
#define PW_BLOCKS 36
#define PREP_BLOCKS (PW_BLOCKS + (PREP_THREADS + 255) / 256)

__global__ __launch_bounds__(256) void prep_all(const float* __restrict__ x,
                                                const float* __restrict__ x_skip,
                                                const float* __restrict__ pos,
                                                const float* __restrict__ pos_skip,
                                                const float* __restrict__ W1,
                                                const float* __restrict__ W2,
                                                ushort* __restrict__ xb,
                                                ushort* __restrict__ xsb,
                                                float4* __restrict__ pos4,
                                                ushort* __restrict__ Bt1a,
                                                ushort* __restrict__ Bt1b,
                                                ushort* __restrict__ Bt2,
                                                float* __restrict__ out) {
    __shared__ ushort tile[64 * 65];
    if (blockIdx.x < PW_BLOCKS) {
        // ---- weight transpose (64x64 LDS tiles, pad 65)
        int bid = blockIdx.x;
        const float* src; ushort* dst; int k0, n0, KD;
        if (bid < 16)      { src = W1;             dst = Bt1a; k0 = (bid >> 2) * 64; n0 = (bid & 3) * 64; KD = 256; }
        else if (bid < 20) { src = W1 + 256 * 256; dst = Bt1b; k0 = 0;               n0 = (bid - 16) * 64; KD = 64; }
        else               { int b2 = bid - 20; src = W2; dst = Bt2; k0 = (b2 >> 2) * 64; n0 = (b2 & 3) * 64; KD = 256; }
        int tx = threadIdx.x & 63, ty = threadIdx.x >> 6;
#pragma unroll
        for (int r = 0; r < 64; r += 4) {
            int k = r + ty;
            tile[k * 65 + tx] = f2bf(src[(size_t)(k0 + k) * 256 + n0 + tx]);
        }
        __syncthreads();
#pragma unroll
        for (int r = 0; r < 64; r += 4) {
            int n = r + ty;
            dst[(size_t)(n0 + n) * KD + k0 + tx] = tile[tx * 65 + n];
        }
        return;
    }
    int t = (blockIdx.x - PW_BLOCKS) * 256 + threadIdx.x;
    if (t < SEG0) {
        float4 v = ((const float4*)x)[t];
        ushort4 p; p.x = f2bf(v.x); p.y = f2bf(v.y); p.z = f2bf(v.z); p.w = f2bf(v.w);
        ((ushort4*)xb)[t] = p;
        return;
    }
    t -= SEG0;
    if (t < SEG1) {
        float4 v = ((const float4*)x_skip)[t];
        ushort4 p; p.x = f2bf(v.x); p.y = f2bf(v.y); p.z = f2bf(v.z); p.w = f2bf(v.w);
        ((ushort4*)xsb)[t] = p;
        return;
    }
    t -= SEG1;
    if (t < SEG5) {
        float4 q;
        q.x = pos[t * 3 + 0]; q.y = pos[t * 3 + 1]; q.z = pos[t * 3 + 2]; q.w = 0.f;
        pos4[t] = q;
        return;
    }
    t -= SEG5;
    if (t < SEG6) {
        out[(size_t)MTOT * OUTD + t] = pos_skip[t];
        return;
    }
    t -= SEG6;
    if (t < SEG7) {
        out[(size_t)MTOT * OUTD + (size_t)MTOT * 3 + t] = (float)(t >> 13);
    }
}

// ---- kernel 2: knn_gemm — heterogeneous dispatch.
// Round-8 result: knn is VALU-issue bound at 86% with ZERO MfmaUtil, while
// gemm_G (data-independent: xb->Gb vs pos4->idxw/wgt) is MFMA/LDS-bound at
// 1 block/CU with zero overlap partner. MFMA and VALU are separate pipes
// that co-schedule at ~max (m114). Merge: blocks 0..255 = gemm (dispatched
// first so they never tail), blocks 256..1279 = r8's knn verbatim. LDS is a
// 36KB union (knn 29.3 / gemm 36). __launch_bounds__(256,4) caps VGPR<=128
// so 4 blocks/CU survive (knn keeps 4 waves/SIMD). gemm's ~15-20us hides
// under knn's VALU minus a ~5% knn slot-sharing stretch.
#define GW_STRIDE 72
#define KNN_BASE 256
__global__ __launch_bounds__(256, 4) void knn_gemm(const float4* __restrict__ pos4,
                                                   const float* __restrict__ pos_skip,
                                                   int* __restrict__ idxw,
                                                   float* __restrict__ wgt,
                                                   const ushort* __restrict__ A,
                                                   const ushort* __restrict__ Bt,
                                                   ushort* __restrict__ Gb) {
    __shared__ __align__(16) char smem[36864];
    int tid = threadIdx.x;
    int wave = tid >> 6;
    int lane = tid & 63;

    if (blockIdx.x < KNN_BASE) {
        // ================= gemm_G: Gb = bf16( xb @ Bt1a^T ) =================
        ushort* wB = (ushort*)smem;                    // 256*72 ushort = 36 KB
        int m0 = blockIdx.x * 64 + wave * 16;
        int lrow = lane & 15;
        int ko = (lane >> 4) * 8;

        floatx4 acc[16];
#pragma unroll
        for (int i = 0; i < 16; ++i) acc[i] = (floatx4){0.f, 0.f, 0.f, 0.f};

        for (int s = 0; s < 4; ++s) {
            if (s) __syncthreads();
            for (int cch = tid; cch < 2048; cch += 256) {
                int n = cch >> 3, koff = (cch & 7) * 8;
                *(short8*)&wB[n * GW_STRIDE + koff] = *(const short8*)(Bt + n * 256 + s * 64 + koff);
            }
            __syncthreads();
            const ushort* ar = A + (size_t)(m0 + lrow) * 256 + s * 64 + ko;
#pragma unroll
            for (int k0 = 0; k0 < 64; k0 += 32) {
                short8 af = *(const short8*)(ar + k0);
#pragma unroll
                for (int nt = 0; nt < 16; ++nt) {
                    short8 bf = *(const short8*)&wB[(nt * 16 + lrow) * GW_STRIDE + k0 + ko];
                    acc[nt] = __builtin_amdgcn_mfma_f32_16x16x32_bf16(af, bf, acc[nt], 0, 0, 0);
                }
            }
        }
        int rbase = (lane >> 4) * 4;
#pragma unroll
        for (int nt = 0; nt < 16; ++nt) {
            int n = nt * 16 + lrow;
#pragma unroll
            for (int r = 0; r < 4; ++r)
                Gb[(size_t)(m0 + rbase + r) * 256 + n] = f2bf(acc[nt][r]);
        }
        return;
    }

    // ================= knn (r8 structure, verbatim semantics) =================
    float* sx = (float*)smem;                      // NC+8
    float* sy = sx + (NC + 8);
    float* sz = sy + (NC + 8);
    float* pd = sz + (NC + 8);                     // 3*192 floats
    int*   pi = (int*)(pd + 3 * 192);              // 3*192 ints  (total 29280 B)

    int kb = blockIdx.x - KNN_BASE;
    int m = kb * 64 + lane;         // all 4 waves: same 64 fine points
    int b = m >> 13;                // whole block inside one cloud
    int jbase = b * NC;

    for (int i = tid; i < NC; i += 256) {
        float4 q = pos4[jbase + i];
        sx[i] = q.x; sy[i] = q.y; sz[i] = q.z;
    }
    float px = pos_skip[m * 3 + 0];
    float py = pos_skip[m * 3 + 1];
    float pz = pos_skip[m * 3 + 2];
    __syncthreads();

    int joff = wave * KCH4;

    float d0 = 1e30f, d1 = 1e30f, d2 = 1e30f;
    int i0 = jbase, i1 = jbase, i2 = jbase;

    // preload window 0 (local j 0..7) into A registers
    float4 ax0 = *(const float4*)&sx[joff],     ax1 = *(const float4*)&sx[joff + 4];
    float4 ay0 = *(const float4*)&sy[joff],     ay1 = *(const float4*)&sy[joff + 4];
    float4 az0 = *(const float4*)&sz[joff],     az1 = *(const float4*)&sz[joff + 4];

    for (int j16 = 0; j16 < KCH4; j16 += 16) {
        // issue prefetch of window B (local j16+8 .. j16+15)
        int jb2 = joff + j16 + 8;
        float4 bx0 = *(const float4*)&sx[jb2],     bx1 = *(const float4*)&sx[jb2 + 4];
        float4 by0 = *(const float4*)&sy[jb2],     by1 = *(const float4*)&sy[jb2 + 4];
        float4 bz0 = *(const float4*)&sz[jb2],     bz1 = *(const float4*)&sz[jb2 + 4];

        // compute + insert window A (j16 .. j16+7) — hides B's LDS latency
        {
            float dd[8];
#pragma unroll
            for (int u = 0; u < 4; ++u) {
                float ax = px - ax0[u], ay = py - ay0[u], az = pz - az0[u];
                dd[u] = ax * ax + ay * ay + az * az;
                float bx = px - ax1[u], by = py - ay1[u], bz = pz - az1[u];
                dd[u + 4] = bx * bx + by * by + bz * bz;
            }
#pragma unroll
            for (int u = 0; u < 8; ++u) {
                if (__any(dd[u] < d2)) {
                    int jj = jbase + joff + j16 + u;
                    TOP3_INS(dd[u], jj, d0, d1, d2, i0, i1, i2);
                }
            }
        }

        // issue prefetch of next window A (local j16+16 .. j16+23).
        // Last iteration of wave 3 reads into the +8 pad; values are dead.
        int jn = joff + j16 + 16;
        ax0 = *(const float4*)&sx[jn];     ax1 = *(const float4*)&sx[jn + 4];
        ay0 = *(const float4*)&sy[jn];     ay1 = *(const float4*)&sy[jn + 4];
        az0 = *(const float4*)&sz[jn];     az1 = *(const float4*)&sz[jn + 4];

        // compute + insert window B (j16+8 .. j16+15)
        {
            float dd[8];
#pragma unroll
            for (int u = 0; u < 4; ++u) {
                float ax = px - bx0[u], ay = py - by0[u], az = pz - bz0[u];
                dd[u] = ax * ax + ay * ay + az * az;
                float bx = px - bx1[u], by = py - by1[u], bz = pz - bz1[u];
                dd[u + 4] = bx * bx + by * by + bz * bz;
            }
#pragma unroll
            for (int u = 0; u < 8; ++u) {
                if (__any(dd[u] < d2)) {
                    int jj = jbase + joff + j16 + 8 + u;
                    TOP3_INS(dd[u], jj, d0, d1, d2, i0, i1, i2);
                }
            }
        }
    }

    if (wave) {
        pd[(wave - 1) * 192 + lane * 3 + 0] = d0;
        pd[(wave - 1) * 192 + lane * 3 + 1] = d1;
        pd[(wave - 1) * 192 + lane * 3 + 2] = d2;
        pi[(wave - 1) * 192 + lane * 3 + 0] = i0;
        pi[(wave - 1) * 192 + lane * 3 + 1] = i1;
        pi[(wave - 1) * 192 + lane * 3 + 2] = i2;
    }
    __syncthreads();
    if (wave == 0) {
        // merge chunk 1..3 partials in chunk order (all chunk-c j < chunk-c+1
        // j; within-partial d0<=d1<=d2 with ascending-j ties) -> identical to
        // the proven knn_merge semantics -> jax top_k order.
#pragma unroll
        for (int c = 0; c < 3; ++c) {
#pragma unroll
            for (int s = 0; s < 3; ++s) {
                float d = pd[c * 192 + lane * 3 + s];
                int jj = pi[c * 192 + lane * 3 + s];
                TOP3_INS(d, jj, d0, d1, d2, i0, i1, i2);
            }
        }
        float w0 = 1.0f / fmaxf(d0, 1e-16f);
        float w1 = 1.0f / fmaxf(d1, 1e-16f);
        float w2 = 1.0f / fmaxf(d2, 1e-16f);
        float inv = 1.0f / (w0 + w1 + w2);
        idxw[m * 3 + 0] = i0;  wgt[m * 3 + 0] = w0 * inv;
        idxw[m * 3 + 1] = i1;  wgt[m * 3 + 1] = w1 * inv;
        idxw[m * 3 + 2] = i2;  wgt[m * 3 + 2] = w2 * inv;
    }
}

// ---- kernel 3: fused  h1 = relu(x_skip@W1b + interp(Gb) + b1);  out = relu(h1@W2 + b2)
#define LDS_STRIDE 264
#define WB_STRIDE 72
__global__ __launch_bounds__(256) void fused_kernel(const ushort* __restrict__ xsb,
                                                    const ushort* __restrict__ Bt1b,
                                                    const ushort* __restrict__ Gb,
                                                    const int* __restrict__ idxw,
                                                    const float* __restrict__ wgt,
                                                    const float* __restrict__ b1,
                                                    const ushort* __restrict__ Bt2,
                                                    const float* __restrict__ b2,
                                                    float* __restrict__ out) {
    __shared__ ushort h1t[4][16 * LDS_STRIDE];     // 33792 B
    __shared__ ushort wB[256 * WB_STRIDE];         // 36864 B
    __shared__ int   sIdx[4][48];
    __shared__ float sWgt[4][48];                  // total ~72 KB -> 2 blk/CU
    int tid = threadIdx.x;
    int wave = tid >> 6, lane = tid & 63;
    int m0 = blockIdx.x * 64 + wave * 16;
    int lrow = lane & 15;
    int ko = (lane >> 4) * 8;
    int rbase = (lane >> 4) * 4;

    if (lane < 48) {
        sIdx[wave][lane] = idxw[m0 * 3 + lane];
        sWgt[wave][lane] = wgt[m0 * 3 + lane];
    }

    const ushort4* Gv = (const ushort4*)Gb;
    const int*   si = sIdx[wave];
    const float* sw = sWgt[wave];
    ushort4 g[4][3];
#define GATHER(slot, i) {                                         \
        int a0 = si[(i) * 3 + 0];                                 \
        int a1 = si[(i) * 3 + 1];                                 \
        int a2 = si[(i) * 3 + 2];                                 \
        g[slot][0] = Gv[(size_t)a0 * 64 + lane];                  \
        g[slot][1] = Gv[(size_t)a1 * 64 + lane];                  \
        g[slot][2] = Gv[(size_t)a2 * 64 + lane]; }

    GATHER(0, 0) GATHER(1, 1) GATHER(2, 2) GATHER(3, 3)

    for (int cch = tid; cch < 2048; cch += 256) {
        int n = cch >> 3, koff = (cch & 7) * 8;
        *(short8*)&wB[n * WB_STRIDE + koff] = *(const short8*)(Bt1b + n * 64 + koff);
    }
    __syncthreads();

    floatx4 acc[16];
#pragma unroll
    for (int i = 0; i < 16; ++i) acc[i] = (floatx4){0.f, 0.f, 0.f, 0.f};
    {
        const ushort* arow = xsb + (size_t)(m0 + lrow) * 64 + ko;
#pragma unroll
        for (int k0 = 0; k0 < 64; k0 += 32) {
            short8 af = *(const short8*)(arow + k0);
#pragma unroll
            for (int nt = 0; nt < 16; ++nt) {
                short8 bf = *(const short8*)&wB[(nt * 16 + lrow) * WB_STRIDE + k0 + ko];
                acc[nt] = __builtin_amdgcn_mfma_f32_16x16x32_bf16(af, bf, acc[nt], 0, 0, 0);
            }
        }
    }

    ushort* ht = h1t[wave];
#pragma unroll
    for (int nt = 0; nt < 16; ++nt) {
        int n = nt * 16 + lrow;
#pragma unroll
        for (int r = 0; r < 4; ++r)
            ht[(rbase + r) * LDS_STRIDE + n] = f2bf(acc[nt][r]);
    }

    {
        float4 bv = ((const float4*)b1)[lane];
#define COMBINE(i) {                                              \
        int s = (i) & 3;                                          \
        float w0 = sw[(i) * 3 + 0], w1 = sw[(i) * 3 + 1], w2 = sw[(i) * 3 + 2]; \
        ushort4 sv = *(const ushort4*)(ht + (i) * LDS_STRIDE + 4 * lane); \
        float4 h;                                                 \
        h.x = fmaxf(bf2f(sv.x) + w0 * bf2f(g[s][0].x) + w1 * bf2f(g[s][1].x) + w2 * bf2f(g[s][2].x) + bv.x, 0.f); \
        h.y = fmaxf(bf2f(sv.y) + w0 * bf2f(g[s][0].y) + w1 * bf2f(g[s][1].y) + w2 * bf2f(g[s][2].y) + bv.y, 0.f); \
        h.z = fmaxf(bf2f(sv.z) + w0 * bf2f(g[s][0].z) + w1 * bf2f(g[s][1].z) + w2 * bf2f(g[s][2].z) + bv.z, 0.f); \
        h.w = fmaxf(bf2f(sv.w) + w0 * bf2f(g[s][0].w) + w1 * bf2f(g[s][1].w) + w2 * bf2f(g[s][2].w) + bv.w, 0.f); \
        ushort4 hp;                                               \
        hp.x = f2bf(h.x); hp.y = f2bf(h.y); hp.z = f2bf(h.z); hp.w = f2bf(h.w); \
        *(ushort4*)(ht + (i) * LDS_STRIDE + 4 * lane) = hp; }

#pragma unroll
        for (int i = 0; i < 12; ++i) { COMBINE(i); GATHER(i & 3, i + 4); }
#pragma unroll
        for (int i = 12; i < 16; ++i) { COMBINE(i); }
#undef GATHER
#undef COMBINE
    }

#pragma unroll
    for (int i = 0; i < 16; ++i) acc[i] = (floatx4){0.f, 0.f, 0.f, 0.f};
    for (int s = 0; s < 4; ++s) {
        __syncthreads();
        for (int cch = tid; cch < 2048; cch += 256) {
            int n = cch >> 3, koff = (cch & 7) * 8;
            *(short8*)&wB[n * WB_STRIDE + koff] = *(const short8*)(Bt2 + n * 256 + s * 64 + koff);
        }
        __syncthreads();
        const ushort* ar = ht + lrow * LDS_STRIDE + s * 64 + ko;
#pragma unroll
        for (int k0 = 0; k0 < 64; k0 += 32) {
            short8 af = *(const short8*)(ar + k0);
#pragma unroll
            for (int nt = 0; nt < 16; ++nt) {
                short8 bf = *(const short8*)&wB[(nt * 16 + lrow) * WB_STRIDE + k0 + ko];
                acc[nt] = __builtin_amdgcn_mfma_f32_16x16x32_bf16(af, bf, acc[nt], 0, 0, 0);
            }
        }
    }
#pragma unroll
    for (int nt = 0; nt < 16; ++nt) {
        int n = nt * 16 + lrow;
        float bv2 = b2[n];
#pragma unroll
        for (int r = 0; r < 4; ++r) {
            float v = fmaxf(acc[nt][r] + bv2, 0.f);
            out[(size_t)(m0 + rbase + r) * OUTD + n] = v;
        }
    }
}

extern "C" void kernel_launch(void* const* d_in, const int* in_sizes, int n_in,
                              void* d_out, int out_size, void* d_ws, size_t ws_size,
                              hipStream_t stream) {
    const float* x        = (const float*)d_in[0];
    const float* pos      = (const float*)d_in[1];
    const float* x_skip   = (const float*)d_in[3];
    const float* pos_skip = (const float*)d_in[4];
    const float* W1       = (const float*)d_in[6];
    const float* b1       = (const float*)d_in[7];
    const float* W2       = (const float*)d_in[8];
    const float* b2       = (const float*)d_in[9];

    char* ws = (char*)d_ws;
    size_t off = 0;
    int*    idxw = (int*)(ws + off);    off += (size_t)MTOT * 3 * 4;      //  768 KB
    float*  wgt  = (float*)(ws + off);  off += (size_t)MTOT * 3 * 4;      //  768 KB
    ushort* xb   = (ushort*)(ws + off); off += (size_t)NCTOT * 256 * 2;   //    8 MB
    ushort* xsb  = (ushort*)(ws + off); off += (size_t)MTOT * 64 * 2;     //    8 MB
    ushort* Gb   = (ushort*)(ws + off); off += (size_t)NCTOT * 256 * 2;   //    8 MB
    ushort* Bt1a = (ushort*)(ws + off); off += (size_t)256 * 256 * 2;     //  128 KB
    ushort* Bt1b = (ushort*)(ws + off); off += (size_t)256 * 64 * 2;      //   32 KB
    ushort* Bt2  = (ushort*)(ws + off); off += (size_t)256 * 256 * 2;     //  128 KB
    float4* pos4 = (float4*)(ws + off); off += (size_t)(NCTOT + 8) * 16;  //  256 KB
    float* out = (float*)d_out;

    prep_all<<<PREP_BLOCKS, 256, 0, stream>>>(
        x, x_skip, pos, pos_skip, W1, W2, xb, xsb, pos4, Bt1a, Bt1b, Bt2, out);
    knn_gemm<<<KNN_BASE + MTOT / 64, 256, 0, stream>>>(
        pos4, pos_skip, idxw, wgt, xb, Bt1a, Gb);
    fused_kernel<<<MTOT / 64, 256, 0, stream>>>(xsb, Bt1b, Gb, idxw, wgt, b1, Bt2, b2, out);
}